// Round 1
// 762.569 us; speedup vs baseline: 1.0519x; 1.0519x over previous
//
#include <hip/hip_runtime.h>

// OctreeMaxPool, two-pass with TRANSPOSED intermediate.
//   Pass 1: pooled_t[g*128 + c] = max over data[c, 8g..8g+7]
//           -- rewritten for fully-contiguous streaming reads + LDS transpose.
//   Pass 2: out[c,m] = idx[m]>=0 ? pooled_t[idx[m]*128 + c] : 0
//           -- branch-free: clipped gather + per-element zero select, so
//              every store is a full 256 B coalesced wave-store.

#define CH  128
#define GPB 64    // groups per block in pass 1 (64 groups = 512 floats = 2 KB/row)

// ---------------- Pass 1: pool + transpose ----------------
// Block 256 threads, tile = 64 groups x 128 channels.
// Read phase: per step, 2 channel rows x 2 KB contiguous (each wave issues
// 1 KB contiguous float4 loads -- canonical streaming). Each thread reduces
// half a group (4 floats); one shfl_xor(1) merges the pair into the group max.
// Transpose via padded LDS tile; write phase emits 64 records x 512 B as
// contiguous 1 KB-per-wave float4 stores.
__global__ __launch_bounds__(256) void pool_t_kernel(
    const float* __restrict__ data,
    float* __restrict__ pooled_t,
    int n,     // N
    int gpc)   // N/8
{
    __shared__ float tile[GPB][CH + 1];   // +1 pad: conflict-free transposed writes

    int t    = threadIdx.x;
    int g0   = blockIdx.x * GPB;
    int lane = t & 127;                   // position along row: floats [4*lane, 4*lane+4)
    int rhf  = t >> 7;                    // which of the 2 rows this step
    int gl   = lane >> 1;                 // local group 0..63
    int h    = lane & 1;                  // half of group

    if (g0 + GPB <= gpc) {                // full tile (always true for N=2^20)
        const float* base = data + (size_t)g0 * 8;
        #pragma unroll 4
        for (int r = 0; r < CH; r += 2) {
            int row = r + rhf;
            float4 a = *(const float4*)(base + (size_t)row * n + lane * 4);
            float m = fmaxf(fmaxf(a.x, a.y), fmaxf(a.z, a.w));
            m = fmaxf(m, __shfl_xor(m, 1));   // merge the two half-groups
            if (h == 0) tile[gl][row] = m;    // conflict-free: bank = (gl*129+row)%32
        }
        __syncthreads();

        // 64 records x 512 B; each wave stores 1 KB contiguous per iteration.
        int cq = t & 31;                  // channel quad
        int r0 = t >> 5;                  // 0..7
        #pragma unroll
        for (int w = 0; w < 8; ++w) {
            int rec = w * 8 + r0;
            float4 v = make_float4(tile[rec][cq * 4 + 0], tile[rec][cq * 4 + 1],
                                   tile[rec][cq * 4 + 2], tile[rec][cq * 4 + 3]);
            *(float4*)(pooled_t + (size_t)(g0 + rec) * CH + cq * 4) = v;
        }
    } else {
        // generic tail (unused at N=2^20, kept for safety)
        for (int g = g0 + t; g < gpc; g += 256) {
            for (int c = 0; c < CH; ++c) {
                const float* p = data + (size_t)c * n + (size_t)g * 8;
                float m = p[0];
                for (int k = 1; k < 8; ++k) m = fmaxf(m, p[k]);
                pooled_t[(size_t)g * CH + c] = m;
            }
        }
    }
}

// ---------------- Pass 2: record gather + zero-pad (branch-free) ----------------
// Thread per (m, half-record). Empty lanes gather record 0 (L1-hot broadcast)
// and select 0 per element -- uniform control flow, fully coalesced stores.
__global__ __launch_bounds__(256) void pad_t_kernel(
    const float* __restrict__ pooled_t,
    const int* __restrict__ child_idx,
    float* __restrict__ out,
    int m_total)
{
    int m = blockIdx.x * 256 + threadIdx.x;
    if (m >= m_total) return;
    int idx  = child_idx[m];
    bool live = (idx >= 0);
    int rec  = live ? idx : 0;
    int c0   = blockIdx.y * 64;

    const float4* recp = (const float4*)(pooled_t + (size_t)rec * CH + c0);
    #pragma unroll
    for (int k = 0; k < 16; ++k) {
        float4 v = recp[k];
        size_t c = (size_t)(c0 + 4 * k);
        out[(c + 0) * m_total + m] = live ? v.x : 0.0f;
        out[(c + 1) * m_total + m] = live ? v.y : 0.0f;
        out[(c + 2) * m_total + m] = live ? v.z : 0.0f;
        out[(c + 3) * m_total + m] = live ? v.w : 0.0f;
    }
}

// ---------------- Fallback: fused single-pass (no workspace) ----------------
__global__ __launch_bounds__(256) void fused_kernel(
    const float* __restrict__ data,
    const int* __restrict__ child_idx,
    float* __restrict__ out,
    int n, int m_total)
{
    int m = blockIdx.x * 256 + threadIdx.x;
    if (m >= m_total) return;
    int idx = child_idx[m];
    int c0 = blockIdx.y * 8;
    if (idx < 0) {
        #pragma unroll
        for (int cc = 0; cc < 8; ++cc)
            out[(size_t)(c0 + cc) * m_total + m] = 0.0f;
        return;
    }
    size_t base = (size_t)idx * 8;
    #pragma unroll
    for (int cc = 0; cc < 8; ++cc) {
        const float4* p = (const float4*)(data + (size_t)(c0 + cc) * n + base);
        float4 a = p[0];
        float4 b = p[1];
        out[(size_t)(c0 + cc) * m_total + m] =
            fmaxf(fmaxf(fmaxf(a.x, a.y), fmaxf(a.z, a.w)),
                  fmaxf(fmaxf(b.x, b.y), fmaxf(b.z, b.w)));
    }
}

extern "C" void kernel_launch(void* const* d_in, const int* in_sizes, int n_in,
                              void* d_out, int out_size, void* d_ws, size_t ws_size,
                              hipStream_t stream) {
    const float* data      = (const float*)d_in[0];
    const int*   child_idx = (const int*)d_in[1];
    float*       out       = (float*)d_out;

    int n   = in_sizes[0] / CH;     // N = 1048576
    int m   = in_sizes[1];          // M = 262144
    int gpc = n / 8;                // 131072
    size_t pooled_bytes = (size_t)gpc * CH * sizeof(float);  // 64 MB

    if (ws_size >= pooled_bytes && (n % 8) == 0) {
        float* pooled_t = (float*)d_ws;
        dim3 b1(256), g1((gpc + GPB - 1) / GPB);
        hipLaunchKernelGGL(pool_t_kernel, g1, b1, 0, stream, data, pooled_t, n, gpc);
        dim3 b2(256), g2((m + 255) / 256, 2);
        hipLaunchKernelGGL(pad_t_kernel, g2, b2, 0, stream, pooled_t, child_idx, out, m);
    } else {
        dim3 b(256), g((m + 255) / 256, CH / 8);
        hipLaunchKernelGGL(fused_kernel, g, b, 0, stream, data, child_idx, out, n, m);
    }
}

// Round 2
// 744.958 us; speedup vs baseline: 1.0767x; 1.0236x over previous
//
#include <hip/hip_runtime.h>

// OctreeMaxPool, two-pass with TRANSPOSED intermediate.
//   Pass 1: pooled_t[g*128 + c] = max over data[c, 8g..8g+7]
//           streaming reads (non-temporal: don't let 512 MB of data evict
//           pooled_t from LLC) + LDS transpose -> contiguous record stores.
//   Pass 2: out[c,m] = idx[m]>=0 ? pooled_t[idx[m]*128 + c] : 0
//           branch-free clipped gather (LLC-resident records) + non-temporal
//           coalesced stores (out is never re-read; don't dirty LLC).
//
// dur_us model: ~650 us of the measured time is two harness 2 GiB workspace
// poison pours (fixed); controllable part is ~640 MB mandatory traffic.

#define CH  128
#define GPB 64    // groups per block in pass 1 (64 groups * 8 floats = 2 KB/row)

typedef float f4 __attribute__((ext_vector_type(4)));

// ---------------- Pass 1: pool + transpose ----------------
// Block 256 threads, tile = 64 groups x 128 channels.
// Per step: 4 rows x 2 KB contiguous; each thread owns ONE full group
// (2 x float4 = 32 B) -> reduce 8 floats, one LDS write, no shuffles.
// Each wave's 64 lanes cover exactly one 2 KB row segment (fully coalesced).
// LDS write banks: row uniform per wave, gl 0..63 -> 2-way (free).
__global__ __launch_bounds__(256) void pool_t_kernel(
    const float* __restrict__ data,
    float* __restrict__ pooled_t,
    int n,     // N
    int gpc)   // N/8
{
    __shared__ float tile[GPB][CH + 1];   // +1 pad: conflict-free transposed reads

    int t  = threadIdx.x;
    int g0 = blockIdx.x * GPB;
    int gl = t & 63;                      // local group 0..63
    int rh = t >> 6;                      // row sub-step 0..3

    if (g0 + GPB <= gpc) {                // full tile (always true for N=2^20)
        const float* base = data + (size_t)(g0 + gl) * 8;
        #pragma unroll 4
        for (int r = 0; r < CH; r += 4) {
            int row = r + rh;
            const f4* p = (const f4*)(base + (size_t)row * n);
            f4 a = __builtin_nontemporal_load(p);
            f4 b = __builtin_nontemporal_load(p + 1);
            tile[gl][row] = fmaxf(fmaxf(fmaxf(a.x, a.y), fmaxf(a.z, a.w)),
                                  fmaxf(fmaxf(b.x, b.y), fmaxf(b.z, b.w)));
        }
        __syncthreads();

        // 64 records x 512 B; each wave stores 1 KB contiguous per iteration.
        int cq = t & 31;                  // channel quad
        int r0 = t >> 5;                  // 0..7
        #pragma unroll
        for (int w = 0; w < 8; ++w) {
            int rec = w * 8 + r0;
            f4 v = { tile[rec][cq * 4 + 0], tile[rec][cq * 4 + 1],
                     tile[rec][cq * 4 + 2], tile[rec][cq * 4 + 3] };
            *(f4*)(pooled_t + (size_t)(g0 + rec) * CH + cq * 4) = v;
        }
    } else {
        // generic tail (unused at N=2^20, kept for safety)
        for (int g = g0 + t; g < gpc; g += 256) {
            for (int c = 0; c < CH; ++c) {
                const float* p = data + (size_t)c * n + (size_t)g * 8;
                float mx = p[0];
                for (int k = 1; k < 8; ++k) mx = fmaxf(mx, p[k]);
                pooled_t[(size_t)g * CH + c] = mx;
            }
        }
    }
}

// ---------------- Pass 2: record gather + zero-pad (branch-free) ----------------
// Thread per (m, half-record). Empty lanes gather record 0 (L1-hot broadcast)
// and select 0 per element -- uniform control flow, fully coalesced 256 B
// wave-stores, non-temporal so out doesn't evict pooled_t mid-kernel.
__global__ __launch_bounds__(256) void pad_t_kernel(
    const float* __restrict__ pooled_t,
    const int* __restrict__ child_idx,
    float* __restrict__ out,
    int m_total)
{
    int m = blockIdx.x * 256 + threadIdx.x;
    if (m >= m_total) return;
    int idx   = child_idx[m];
    bool live = (idx >= 0);
    int rec   = live ? idx : 0;
    int c0    = blockIdx.y * 64;

    const f4* recp = (const f4*)(pooled_t + (size_t)rec * CH + c0);
    #pragma unroll
    for (int k = 0; k < 16; ++k) {
        f4 v = recp[k];
        size_t c = (size_t)(c0 + 4 * k);
        __builtin_nontemporal_store(live ? v.x : 0.0f, &out[(c + 0) * m_total + m]);
        __builtin_nontemporal_store(live ? v.y : 0.0f, &out[(c + 1) * m_total + m]);
        __builtin_nontemporal_store(live ? v.z : 0.0f, &out[(c + 2) * m_total + m]);
        __builtin_nontemporal_store(live ? v.w : 0.0f, &out[(c + 3) * m_total + m]);
    }
}

// ---------------- Fallback: fused single-pass (no workspace) ----------------
__global__ __launch_bounds__(256) void fused_kernel(
    const float* __restrict__ data,
    const int* __restrict__ child_idx,
    float* __restrict__ out,
    int n, int m_total)
{
    int m = blockIdx.x * 256 + threadIdx.x;
    if (m >= m_total) return;
    int idx = child_idx[m];
    int c0 = blockIdx.y * 8;
    if (idx < 0) {
        #pragma unroll
        for (int cc = 0; cc < 8; ++cc)
            out[(size_t)(c0 + cc) * m_total + m] = 0.0f;
        return;
    }
    size_t base = (size_t)idx * 8;
    #pragma unroll
    for (int cc = 0; cc < 8; ++cc) {
        const f4* p = (const f4*)(data + (size_t)(c0 + cc) * n + base);
        f4 a = p[0];
        f4 b = p[1];
        out[(size_t)(c0 + cc) * m_total + m] =
            fmaxf(fmaxf(fmaxf(a.x, a.y), fmaxf(a.z, a.w)),
                  fmaxf(fmaxf(b.x, b.y), fmaxf(b.z, b.w)));
    }
}

extern "C" void kernel_launch(void* const* d_in, const int* in_sizes, int n_in,
                              void* d_out, int out_size, void* d_ws, size_t ws_size,
                              hipStream_t stream) {
    const float* data      = (const float*)d_in[0];
    const int*   child_idx = (const int*)d_in[1];
    float*       out       = (float*)d_out;

    int n   = in_sizes[0] / CH;     // N = 1048576
    int m   = in_sizes[1];          // M = 262144
    int gpc = n / 8;                // 131072
    size_t pooled_bytes = (size_t)gpc * CH * sizeof(float);  // 64 MB

    if (ws_size >= pooled_bytes && (n % 8) == 0) {
        float* pooled_t = (float*)d_ws;
        dim3 b1(256), g1((gpc + GPB - 1) / GPB);
        hipLaunchKernelGGL(pool_t_kernel, g1, b1, 0, stream, data, pooled_t, n, gpc);
        dim3 b2(256), g2((m + 255) / 256, 2);
        hipLaunchKernelGGL(pad_t_kernel, g2, b2, 0, stream, pooled_t, child_idx, out, m);
    } else {
        dim3 b(256), g((m + 255) / 256, CH / 8);
        hipLaunchKernelGGL(fused_kernel, g, b, 0, stream, data, child_idx, out, n, m);
    }
}